// Round 12
// baseline (336.784 us; speedup 1.0000x reference)
//
#include <hip/hip_runtime.h>
#include <stdint.h>

#define IN_C 128
#define OUT_C 64
#define NEG_SLOPE 0.2f
#define RB 256       // blocks in the tgt-partition kernel
#define PTPB 1024    // threads/block in k_part_t: 16 waves/CU hides the aj-gather latency (r10 lesson)
#define RBINS 512    // coarse bins (node>>8, node<131072)
#define SCAP 5120    // strided bucket capacity (Binomial mu=4352 sigma=64 -> 12 sigma); always fits LDS stage
#define SGRID (RBINS * SCAP)   // 2,621,440 strided positions
#define KC 8                   // gemm k-chunk
#define GR 64                  // gemm rows/block (64-row 1-wave tiles: grid 1563 ~ 6.1/CU, r11 lesson)
#define SXW 96                 // sx words per kl: 8 rowgroups * 12 (8 rows + 4 pad)

typedef unsigned int u32;
typedef unsigned char u8;
typedef unsigned long long u64;

// ---------------- helpers ----------------
__device__ __forceinline__ u32 fenc(float f) {
  u32 u = __float_as_uint(f);
  return (u & 0x80000000u) ? ~u : (u | 0x80000000u);
}
__device__ __forceinline__ u64 key64(float v, int i) {
  return (((u64)fenc(v)) << 32) | (u64)(0xffffffffu - (u32)i);
}

// ---------------- h = x @ W + fused ai/aj epilogue ----------------
// 64-row, 64-thread (1-wave) blocks, 8x8/thread. K in 16 chunks of 8.
// Grid 1563 ~ 6.1 blocks/CU (vs 782 ~ 3.05: 4th-round quantization wasted ~25%);
// 35 KB LDS -> 4 independent 1-wave blocks resident/CU; intra-wave barriers ~free.
// JOURNAL: r4 global float atomics for asum = 2x slower (cross-XCD HBM RMW).
//          r6 split-K = +3.3M LDS bank conflicts in 256B-stride merge epilogue.
//          r7 aggregate via 2 arrays = 2x requests -> 89us; u64 pair is load-bearing.
//          r8 bucket-hole straggler nodes = +25us in aggregate (clamp fixed, r9).
//          r9 rpass2 serial aj-gather -> moved to part_t; r10 part_t 1024-thr.
__global__ __launch_bounds__(64) void k_gemm(const float* __restrict__ x,
                                             const float* __restrict__ w,
                                             const float* __restrict__ att,
                                             float* __restrict__ h,
                                             float* __restrict__ ai, float* __restrict__ aj,
                                             int N) {
  __shared__ float sw[IN_C * OUT_C];   // 32 KB
  __shared__ float sx[KC * SXW];       // 3 KB
  int tid = threadIdx.x;               // 0..63 (one wave)
  int rbase = blockIdx.x * GR;

  for (int i = tid; i < (IN_C * OUT_C) / 4; i += 64)
    ((float4*)sw)[i] = ((const float4*)w)[i];

  int c0 = (tid & 7) * 8;        // 8 col groups
  int rg = tid >> 3;             // 8 row groups x 8 rows
  int sxbase = rg * 12;
  float acc[8][8];
#pragma unroll
  for (int i = 0; i < 8; i++)
#pragma unroll
    for (int j = 0; j < 8; j++) acc[i][j] = 0.f;

  // staging: thread = row; loads its row's 8 k-values (2 contiguous float4)
  int grow = rbase + tid;
  int base = (tid >> 3) * 12 + (tid & 7);   // phys(row) in a plane
  const float* xp = &x[(size_t)grow * IN_C];

  float4 pv0 = make_float4(0.f, 0.f, 0.f, 0.f);
  float4 pv1 = make_float4(0.f, 0.f, 0.f, 0.f);
  if (grow < N) {
    pv0 = *(const float4*)&xp[0];
    pv1 = *(const float4*)&xp[4];
  }

  for (int kb = 0; kb < IN_C; kb += KC) {
    __syncthreads();
    sx[0 * SXW + base] = pv0.x;
    sx[1 * SXW + base] = pv0.y;
    sx[2 * SXW + base] = pv0.z;
    sx[3 * SXW + base] = pv0.w;
    sx[4 * SXW + base] = pv1.x;
    sx[5 * SXW + base] = pv1.y;
    sx[6 * SXW + base] = pv1.z;
    sx[7 * SXW + base] = pv1.w;
    // T14: issue next chunk's loads; latency hides under the FMA burst
    if (kb + KC < IN_C && grow < N) {
      pv0 = *(const float4*)&xp[kb + KC];
      pv1 = *(const float4*)&xp[kb + KC + 4];
    }
    __syncthreads();
#pragma unroll
    for (int kl = 0; kl < KC; ++kl) {
      int kg = kb + kl;
      float xr[8], wv[8];
      *(float4*)&xr[0] = *(const float4*)&sx[kl * SXW + sxbase];
      *(float4*)&xr[4] = *(const float4*)&sx[kl * SXW + sxbase + 4];
      *(float4*)&wv[0] = *(const float4*)&sw[kg * OUT_C + c0];
      *(float4*)&wv[4] = *(const float4*)&sw[kg * OUT_C + c0 + 4];
#pragma unroll
      for (int i = 0; i < 8; ++i)
#pragma unroll
        for (int j = 0; j < 8; ++j)
          acc[i][j] += xr[i] * wv[j];
    }
  }

  float pi[8], pj[8];
#pragma unroll
  for (int i = 0; i < 8; ++i) { pi[i] = 0.f; pj[i] = 0.f; }
#pragma unroll
  for (int j = 0; j < 8; ++j) {
    float a0 = att[c0 + j], a1 = att[OUT_C + c0 + j];
#pragma unroll
    for (int i = 0; i < 8; ++i) {
      pi[i] += acc[i][j] * a0;
      pj[i] += acc[i][j] * a1;
    }
  }
#pragma unroll
  for (int o = 1; o < 8; o <<= 1) {
#pragma unroll
    for (int i = 0; i < 8; ++i) {
      pi[i] += __shfl_xor(pi[i], o);
      pj[i] += __shfl_xor(pj[i], o);
    }
  }
#pragma unroll
  for (int i = 0; i < 8; ++i) {
    int row = rbase + rg * 8 + i;
    if (row < N) {
      *(float4*)&h[(size_t)row * OUT_C + c0]     = make_float4(acc[i][0], acc[i][1], acc[i][2], acc[i][3]);
      *(float4*)&h[(size_t)row * OUT_C + c0 + 4] = make_float4(acc[i][4], acc[i][5], acc[i][6], acc[i][7]);
      if ((tid & 7) == 0) { ai[row] = pi[i]; aj[row] = pj[i]; }
    }
  }
}

// ---------------- fused tgt partition: hist + strided reservation + scatter + aj gather ----------------
// 1024 threads/block (16 waves/CU): the per-edge aj[src] gather latency is
// covered by TLP. Packs item u64 = ((tgt&255)<<24 | src) << 32 | f32(aj[src]).
__global__ __launch_bounds__(1024) void k_part_t(const int* __restrict__ src, const int* __restrict__ tgt,
                                                 const float* __restrict__ aj,
                                                 int E, int EN, int chunk,
                                                 u32* __restrict__ gcurT, u64* __restrict__ bufS,
                                                 u32* __restrict__ sel, u32 kSel) {
  __shared__ u32 lh[RBINS];
  __shared__ u32 cur[RBINS];
  int tid = threadIdx.x, b = blockIdx.x;
  if (b == 0 && tid == 0) { sel[0] = 0u; sel[1] = 0u; sel[2] = kSel; sel[3] = 0u; }
  for (int d = tid; d < RBINS; d += PTPB) lh[d] = 0u;
  __syncthreads();
  int lo = b * chunk, hi = min(lo + chunk, EN);
  for (int e = lo + tid; e < hi; e += PTPB) {
    int t = (e < E) ? tgt[e] : e - E;
    atomicAdd(&lh[((u32)t) >> 8], 1u);
  }
  __syncthreads();
  for (int d = tid; d < RBINS; d += PTPB) {
    u32 c = lh[d];
    cur[d] = c ? (u32)(d * SCAP) + atomicAdd(&gcurT[d], c) : 0u;
  }
  __syncthreads();
  for (int e = lo + tid; e < hi; e += PTPB) {
    int s, t;
    if (e < E) { s = src[e]; t = tgt[e]; } else { s = t = e - E; }
    u32 tb = ((u32)t) >> 8;
    u32 p = atomicAdd(&cur[tb], 1u);
    if (p < (tb + 1u) * SCAP) {
      float av = aj[s];
      bufS[p] = (((u64)((((u32)t & 255u) << 24) | (u32)s)) << 32) | (u64)__float_as_uint(av);
    }
  }
}

// ---------------- fine partition + CSR offsets + LDS-ONLY SOFTMAX + fused src scatter ----
__global__ __launch_bounds__(256) void k_rpass2(const u64* __restrict__ in, u32* __restrict__ out,
                                                const u32* __restrict__ gcurT, u32* __restrict__ gcurS,
                                                u32* __restrict__ offT,
                                                const float* __restrict__ ai,
                                                float* __restrict__ alpha,
                                                u64* __restrict__ pv,
                                                int N) {
  __shared__ u32 hist[256];
  __shared__ u32 sc[256];
  __shared__ u32 lhs[RBINS];
  __shared__ u32 stage[SCAP];    // 20 KB: items
  __shared__ float stageV[SCAP]; // 20 KB: aj -> a -> v -> vnorm
  int tid = threadIdx.x, d = blockIdx.x;
  u32 start = (u32)(d * SCAP);
  u32 cntb = min(gcurT[d], (u32)SCAP);
  u32 end = start + cntb;
  int sz = (int)cntb;
  hist[tid] = 0u;
  for (int dd = tid; dd < RBINS; dd += 256) lhs[dd] = 0u;
  __syncthreads();
  for (u32 p = start + tid; p < end; p += 256) {
    u32 it = (u32)(in[p] >> 32);
    atomicAdd(&hist[it >> 24], 1u);
    atomicAdd(&lhs[(it & 0xffffffu) >> 8], 1u);
  }
  __syncthreads();
  // reserve src-bucket ranges; global-atomic latency hides under scan+sort
  for (int dd = tid; dd < RBINS; dd += 256) {
    u32 c = lhs[dd];
    lhs[dd] = c ? (u32)(dd * SCAP) + atomicAdd(&gcurS[dd], c) : 0u;
  }
  u32 hv = hist[tid];
  sc[tid] = hv;
  __syncthreads();
  for (int o = 1; o < 256; o <<= 1) {
    u32 t = (tid >= o) ? sc[tid - o] : 0u;
    __syncthreads();
    sc[tid] += t;
    __syncthreads();
  }
  u32 excl = sc[tid] - hv;
  int node = (d << 8) + tid;
  if (node < N) offT[node] = start + excl;
  if (node == N - 1) offT[N] = start + sc[tid];
  hist[tid] = excl;   // running cursor
  __syncthreads();
  for (u32 p = start + tid; p < end; p += 256) {
    u64 it64 = in[p];
    u32 it = (u32)(it64 >> 32);
    u32 lp = atomicAdd(&hist[it >> 24], 1u);
    stage[lp] = it;
    stageV[lp] = __uint_as_float((u32)it64);
  }
  __syncthreads();
  // CSR items out (global writes overlap the softmax below)
  for (int i = tid; i < sz; i += 256) out[start + i] = stage[i];
  // ---- per-node softmax: pure LDS (aj pre-gathered into stageV) ----
  if (node < N) {
    int lb = (tid > 0) ? (int)sc[tid - 1] : 0;
    int le = (int)sc[tid];
    float an = ai[node];
    float mx = -1e30f;
    for (int i = lb; i < le; ++i) {
      float a = an + stageV[i];
      a = a > 0.f ? a : NEG_SLOPE * a;
      stageV[i] = a;
      mx = fmaxf(mx, a);
    }
    float sm = 0.f;
    for (int i = lb; i < le; ++i) {
      float v = expf(stageV[i] - mx);
      stageV[i] = v;
      sm += v;
    }
    float inv = 1.f / (sm + 1e-16f);
    for (int i = lb; i < le; ++i) {
      float vn = stageV[i] * inv;
      stageV[i] = vn;
      alpha[start + i] = vn;
    }
  }
  __syncthreads();
  // ---- src scatter from LDS into reserved ranges: one packed u64 per edge ----
  for (u32 p = start + tid; p < end; p += 256) {
    int i = (int)(p - start);
    u32 sp = stage[i] & 0xffffffu;
    u32 sb = sp >> 8;
    u32 pos = atomicAdd(&lhs[sb], 1u);
    if (pos < (sb + 1u) * SCAP)
      pv[pos] = (((u64)(sp & 255u)) << 32) | (u64)__float_as_uint(stageV[i]);
  }
}

// ---------------- per-bucket alpha_sum accumulation + FUSED radix pass 0 ----------------
__global__ __launch_bounds__(256) void k_asum_acc(const u64* __restrict__ pv,
                                                  const u32* __restrict__ gcurS,
                                                  float* __restrict__ asum,
                                                  u32* __restrict__ hist8, u32* __restrict__ done,
                                                  u32* __restrict__ sel, int N, int nblk) {
  __shared__ float sums[256];
  __shared__ u32 lh[256];
  __shared__ u32 s[256];
  __shared__ u32 sres;
  int tid = threadIdx.x, d = blockIdx.x;
  u32 start = (u32)(d * SCAP);
  u32 end = start + min(gcurS[d], (u32)SCAP);
  sums[tid] = 0.f;
  __syncthreads();
  for (u32 p = start + tid; p < end; p += 256) {
    u64 it = pv[p];
    atomicAdd(&sums[(u32)(it >> 32)], __uint_as_float((u32)it));
  }
  __syncthreads();
  int node = d * 256 + tid;
  u32 bin = 256u;
  if (node < N) {
    float v = sums[tid];
    asum[node] = v;
    bin = (u32)(key64(v, node) >> 56) & 255u;
  }
  lh[tid] = 0u;
  __syncthreads();
  if (bin < 256u) atomicAdd(&lh[bin], 1u);
  __syncthreads();
  if (lh[tid]) atomicAdd(&hist8[tid], lh[tid]);
  __syncthreads();
  if (tid == 0)
    sres = __hip_atomic_fetch_add(&done[0], 1u, __ATOMIC_ACQ_REL, __HIP_MEMORY_SCOPE_AGENT);
  __syncthreads();
  if (sres == (u32)(nblk - 1)) {
    u32 krem = sel[2];
    u32 hv = __hip_atomic_load(&hist8[255 - tid], __ATOMIC_RELAXED, __HIP_MEMORY_SCOPE_AGENT);
    s[tid] = hv;
    __syncthreads();
    for (int o = 1; o < 256; o <<= 1) {
      u32 t = (tid >= o) ? s[tid - o] : 0u;
      __syncthreads();
      s[tid] += t;
      __syncthreads();
    }
    u32 cum = s[tid], prev = (tid > 0) ? s[tid - 1] : 0u;
    if (cum >= krem && prev < krem) {
      ((u64*)sel)[0] = (u64)(u32)(255 - tid);
      sel[2] = krem - prev;
    }
  }
}

// ---------------- radix pass 1 (generic): hist + append + last-block pick ----------------
__global__ __launch_bounds__(256) void k_histpick(const float* __restrict__ asum,
                                                  u32* __restrict__ list_out, u32* __restrict__ cnt_out,
                                                  u32* __restrict__ hist8, u32* __restrict__ done,
                                                  u32* __restrict__ sel, int N, int nblk) {
  __shared__ u32 lh[256];
  __shared__ u32 sres;
  __shared__ u32 s[256];
  int tid = threadIdx.x;
  lh[tid] = 0u;
  __syncthreads();
  u64 prefix = ((const u64*)sel)[0];
  int i = blockIdx.x * 256 + tid;
  if (i < N) {
    u64 k = key64(asum[i], i);
    if ((k >> 56) == prefix) {
      atomicAdd(&lh[(u32)(k >> 48) & 255u], 1u);
      u32 p = atomicAdd(cnt_out, 1u);
      list_out[p] = (u32)i;
    }
  }
  __syncthreads();
  if (lh[tid]) atomicAdd(&hist8[256 + tid], lh[tid]);
  __syncthreads();
  if (tid == 0)
    sres = __hip_atomic_fetch_add(&done[1], 1u, __ATOMIC_ACQ_REL, __HIP_MEMORY_SCOPE_AGENT);
  __syncthreads();
  if (sres == (u32)(nblk - 1)) {
    u32 krem = sel[2];
    u32 hv = __hip_atomic_load(&hist8[256 + (255 - tid)], __ATOMIC_RELAXED,
                               __HIP_MEMORY_SCOPE_AGENT);
    s[tid] = hv;
    __syncthreads();
    for (int o = 1; o < 256; o <<= 1) {
      u32 t = (tid >= o) ? s[tid - o] : 0u;
      __syncthreads();
      s[tid] += t;
      __syncthreads();
    }
    u32 cum = s[tid], prev = (tid > 0) ? s[tid - 1] : 0u;
    if (cum >= krem && prev < krem) {
      ((u64*)sel)[0] = (prefix << 8) | (u64)(u32)(255 - tid);
      sel[2] = krem - prev;
    }
  }
}

// ---------------- radix pass 2 + in-block pass 3 + tie-break finish ----------------
__global__ __launch_bounds__(256) void k_histpick_final(const float* __restrict__ asum,
                                                        const u32* __restrict__ list_in, const u32* __restrict__ cnt_in,
                                                        u32* __restrict__ list_out, u32* __restrict__ cnt_out,
                                                        u32* __restrict__ hist8, u32* __restrict__ done,
                                                        u32* __restrict__ sel, int nblk) {
  __shared__ u32 lh[256];
  __shared__ u32 s[256];
  __shared__ u32 sres;
  __shared__ u64 keys[2048];
  __shared__ u32 cc;
  __shared__ u64 sprefix;
  __shared__ u32 skrem;
  int tid = threadIdx.x;
  lh[tid] = 0u;
  __syncthreads();
  u64 prefix = ((const u64*)sel)[0];   // 2 bytes
  u32 n = *cnt_in;
  u32 i = blockIdx.x * 256 + tid;
  if (i < n) {
    int idx = (int)list_in[i];
    u64 k = key64(asum[idx], idx);
    if ((k >> 48) == prefix) {
      atomicAdd(&lh[(u32)(k >> 40) & 255u], 1u);
      u32 p = atomicAdd(cnt_out, 1u);
      list_out[p] = (u32)idx;
    }
  }
  __syncthreads();
  if (lh[tid]) atomicAdd(&hist8[512 + tid], lh[tid]);
  __syncthreads();
  if (tid == 0)
    sres = __hip_atomic_fetch_add(&done[2], 1u, __ATOMIC_ACQ_REL, __HIP_MEMORY_SCOPE_AGENT);
  __syncthreads();
  if (sres != (u32)(nblk - 1)) return;
  u32 krem = sel[2];
  u32 hv = __hip_atomic_load(&hist8[512 + (255 - tid)], __ATOMIC_RELAXED, __HIP_MEMORY_SCOPE_AGENT);
  s[tid] = hv;
  __syncthreads();
  for (int o = 1; o < 256; o <<= 1) {
    u32 t = (tid >= o) ? s[tid - o] : 0u;
    __syncthreads();
    s[tid] += t;
    __syncthreads();
  }
  {
    u32 cum = s[tid], prev = (tid > 0) ? s[tid - 1] : 0u;
    if (cum >= krem && prev < krem) { sprefix = (prefix << 8) | (u64)(u32)(255 - tid); skrem = krem - prev; }
  }
  __syncthreads();
  u64 pfx3 = sprefix;
  u32 krem3 = skrem;
  u32 n3 = *cnt_out;
  lh[tid] = 0u;
  __syncthreads();
  for (u32 j = tid; j < n3; j += 256) {
    int idx = (int)list_out[j];
    u64 k = key64(asum[idx], idx);
    if ((k >> 40) == pfx3) atomicAdd(&lh[(u32)(k >> 32) & 255u], 1u);
  }
  __syncthreads();
  s[tid] = lh[255 - tid];
  __syncthreads();
  for (int o = 1; o < 256; o <<= 1) {
    u32 t = (tid >= o) ? s[tid - o] : 0u;
    __syncthreads();
    s[tid] += t;
    __syncthreads();
  }
  {
    u32 cum = s[tid], prev = (tid > 0) ? s[tid - 1] : 0u;
    if (cum >= krem3 && prev < krem3) { sprefix = (pfx3 << 8) | (u64)(u32)(255 - tid); skrem = krem3 - prev; }
  }
  if (tid == 0) cc = 0u;
  __syncthreads();
  u32 fsel = (u32)sprefix;
  u32 kremF = skrem;
  for (u32 j = tid; j < n3; j += 256) {
    int idx = (int)list_out[j];
    u64 k = key64(asum[idx], idx);
    if ((u32)(k >> 32) == fsel) {
      u32 p = atomicAdd(&cc, 1u);
      if (p < 2048) keys[p] = k;
    }
  }
  __syncthreads();
  int C = (int)min(cc, 2048u);
  for (int j = tid; j < C; j += 256) {
    u64 k = keys[j];
    u32 rank = 0;
    for (int q = 0; q < C; ++q)
      if (keys[q] > k) rank++;
    if (rank == kremF - 1) ((u64*)sel)[0] = k;
  }
}

// ---------------- node mask ----------------
__global__ __launch_bounds__(256) void k_node_mask(const float* __restrict__ asum,
                                                   const u32* __restrict__ sel,
                                                   u32* __restrict__ nm,
                                                   float* __restrict__ out_node, int N) {
  int i = blockIdx.x * 256 + threadIdx.x;
  if (i >= N) return;
  u64 T = ((const u64*)sel)[0];
  bool m = key64(asum[i], i) >= T;
  nm[i] = m ? 1u : 0u;
  out_node[i] = m ? 1.f : 0.f;
}

// ---------------- raw edge mask + premasked u64 pairs (holes skipped) ----------------
__global__ __launch_bounds__(256) void k_mask(const int* __restrict__ src, const int* __restrict__ tgt,
                                              const u32* __restrict__ nm,
                                              const u32* __restrict__ csr, const float* __restrict__ alpha,
                                              const u32* __restrict__ gcurT,
                                              float* __restrict__ out_edge, u64* __restrict__ pair,
                                              int E, int EN) {
  int q = blockIdx.x * 256 + threadIdx.x;
  if (q < EN) {
    int s, t;
    if (q < E) { s = src[q]; t = tgt[q]; } else { s = t = q - E; }
    out_edge[q] = (nm[s] && nm[t]) ? 1.f : 0.f;
  }
  if (q < SGRID) {
    u32 b = (u32)q / (u32)SCAP;
    u32 r = (u32)q - b * (u32)SCAP;
    if (r < min(gcurT[b], (u32)SCAP)) {   // holes never read (aggregate clamps)
      u32 sp = csr[q] & 0xffffffu;
      u32 ab = nm[sp] ? __float_as_uint(alpha[q]) : 0u;
      pair[q] = (((u64)sp) << 32) | ab;
    }
  }
}

// ---------------- aggregate: 8-slot pipeline, single u64 load/edge, bucket-end clamp ----------------
__global__ __launch_bounds__(256) void k_aggregate(const u32* __restrict__ off,
                                                   const u64* __restrict__ pair,
                                                   const float* __restrict__ h,
                                                   const u32* __restrict__ nm,
                                                   const u32* __restrict__ gcurT,
                                                   float* __restrict__ out, int N) {
  int node = blockIdx.x * 4 + (threadIdx.x >> 6);
  int lane = threadIdx.x & 63;
  int g = lane >> 4;
  int c = lane & 15;
  if (node >= N) return;
  float4 acc = make_float4(0.f, 0.f, 0.f, 0.f);
  if (nm[node]) {
    u32 bkt = (u32)node >> 8;
    u32 bend = bkt * (u32)SCAP + min(gcurT[bkt], (u32)SCAP);
    u32 b = off[node];
    u32 e2 = min(off[node + 1], bend);   // clamp: bucket-last node must not span holes (r8)
    for (u32 p0 = b; p0 < e2; p0 += 32) {
      u64 pr[8];
      float av[8];
      u32 sv[8];
#pragma unroll
      for (int q = 0; q < 8; ++q) {
        u32 p = p0 + q * 4 + (u32)g;
        bool ok = p < e2;
        pr[q] = pair[ok ? p : b];
        av[q] = ok ? __uint_as_float((u32)pr[q]) : 0.f;
        sv[q] = (u32)(pr[q] >> 32);
      }
      float4 hv[8];
#pragma unroll
      for (int q = 0; q < 8; ++q) {
        hv[q] = make_float4(0.f, 0.f, 0.f, 0.f);
        if (av[q] != 0.f)
          hv[q] = *(const float4*)&h[(size_t)sv[q] * OUT_C + c * 4];
      }
#pragma unroll
      for (int q = 0; q < 8; ++q) {
        acc.x += av[q] * hv[q].x;
        acc.y += av[q] * hv[q].y;
        acc.z += av[q] * hv[q].z;
        acc.w += av[q] * hv[q].w;
      }
    }
#pragma unroll
    for (int o = 16; o < 64; o <<= 1) {
      acc.x += __shfl_xor(acc.x, o);
      acc.y += __shfl_xor(acc.y, o);
      acc.z += __shfl_xor(acc.z, o);
      acc.w += __shfl_xor(acc.w, o);
    }
  }
  if (g == 0)
    *(float4*)&out[(size_t)node * OUT_C + c * 4] = acc;
}

// ---------------- launch ----------------
extern "C" void kernel_launch(void* const* d_in, const int* in_sizes, int n_in,
                              void* d_out, int out_size, void* d_ws, size_t ws_size,
                              hipStream_t stream) {
  const float* x   = (const float*)d_in[0];
  const float* w   = (const float*)d_in[1];
  const float* att = (const float*)d_in[2];
  const int*   ei  = (const int*)d_in[3];

  int N = in_sizes[0] / IN_C;
  int E = in_sizes[3] / 2;
  int EN = E + N;
  const int* src = ei;
  const int* tgt = ei + E;

  float* out      = (float*)d_out;
  float* out_edge = out + (size_t)N * OUT_C;
  float* out_node = out_edge + (size_t)EN;

  char* p = (char*)d_ws;
  auto alloc = [&](size_t bytes) -> char* {
    char* r = p;
    p += (bytes + 255) & ~(size_t)255;
    return r;
  };
  float* h     = (float*)alloc((size_t)N * OUT_C * 4);
  float* ai    = (float*)alloc((size_t)N * 4);
  float* aj    = (float*)alloc((size_t)N * 4);
  u64*   stg   = (u64*)alloc((size_t)SGRID * 8);   // part_t out: (item<<32 | f32 aj[src])
  u32*   bufA  = (u32*)alloc((size_t)SGRID * 4);   // CSR items
  float* alpha = (float*)alloc((size_t)SGRID * 4); // alpha in strided CSR order
  u64*   pv    = (u64*)alloc((size_t)SGRID * 8);   // src-pairs, then REUSED as agg pairs
  u32*   offT  = (u32*)alloc((size_t)(N + 1) * 4);
  float* asum  = (float*)alloc((size_t)N * 4);
  u32*   nm    = (u32*)alloc((size_t)N * 4);
  u32*   listA = (u32*)alloc((size_t)N * 4);
  u32*   listB = (u32*)alloc((size_t)N * 4);
  u32*   zb    = (u32*)alloc((RBINS + RBINS + 2048 + 8 + 8) * 4);
  u32*   gcurT = zb;
  u32*   gcurS = zb + RBINS;
  u32*   hist8 = zb + 2 * RBINS;
  u32*   done  = zb + 2 * RBINS + 2048;
  u32*   cnt   = zb + 2 * RBINS + 2048 + 8;
  u32*   sel   = (u32*)alloc(256);

  u64*   pair  = pv;   // alias: pv consumed by k_asum_acc before k_mask writes pair

  u32 kSel = (u32)((N + 1) / 2);
  int chunk = (EN + RB - 1) / RB;
  int gGemm = (N + GR - 1) / GR;   // 1563 blocks ~ 6.1/CU
  int gN = (N + 255) / 256;
  int gS = (SGRID + 255) / 256;   // covers EN too
  int gNode4 = (N + 3) / 4;

  hipMemsetAsync(zb, 0, (RBINS + RBINS + 2048 + 8 + 8) * 4, stream);

  k_gemm<<<gGemm, 64, 0, stream>>>(x, w, att, h, ai, aj, N);

  k_part_t<<<RB, PTPB, 0, stream>>>(src, tgt, aj, E, EN, chunk, gcurT, stg, sel, kSel);
  k_rpass2<<<RBINS, 256, 0, stream>>>(stg, bufA, gcurT, gcurS, offT, ai, alpha, pv, N);
  k_asum_acc<<<RBINS, 256, 0, stream>>>(pv, gcurS, asum, hist8, done, sel, N, RBINS);

  k_histpick<<<gN, 256, 0, stream>>>(asum, listA, &cnt[1], hist8, done, sel, N, gN);
  k_histpick_final<<<gN, 256, 0, stream>>>(asum, listA, &cnt[1], listB, &cnt[2],
                                           hist8, done, sel, gN);

  k_node_mask<<<gN, 256, 0, stream>>>(asum, sel, nm, out_node, N);
  k_mask<<<gS, 256, 0, stream>>>(src, tgt, nm, bufA, alpha, gcurT, out_edge, pair, E, EN);
  k_aggregate<<<gNode4, 256, 0, stream>>>(offT, pair, h, nm, gcurT, out, N);
}

// Round 13
// 315.768 us; speedup vs baseline: 1.0666x; 1.0666x over previous
//
#include <hip/hip_runtime.h>
#include <stdint.h>

#define IN_C 128
#define OUT_C 64
#define NEG_SLOPE 0.2f
#define RB 256       // blocks in the tgt-partition kernel
#define PTPB 1024    // threads/block in k_part_t: 16 waves/CU hides the aj-gather latency (r10 lesson)
#define RBINS 512    // coarse bins (node>>8, node<131072)
#define SCAP 5120    // strided bucket capacity (Binomial mu=4352 sigma=64 -> 12 sigma); always fits LDS stage
#define SGRID (RBINS * SCAP)   // 2,621,440 strided positions
#define KC 8                   // gemm k-chunk
#define SXW 192                // sx words per kl: 16 rowgroups * 12 (8 rows + 4 pad)

typedef unsigned int u32;
typedef unsigned char u8;
typedef unsigned long long u64;

// ---------------- helpers ----------------
__device__ __forceinline__ u32 fenc(float f) {
  u32 u = __float_as_uint(f);
  return (u & 0x80000000u) ? ~u : (u | 0x80000000u);
}
__device__ __forceinline__ u64 key64(float v, int i) {
  return (((u64)fenc(v)) << 32) | (u64)(0xffffffffu - (u32)i);
}

// ---------------- h = x @ W + fused ai/aj epilogue ----------------
// 128-row/128-thread tile, 8x8/thread, K in 16 chunks of 8 — but W staged
// PER-CHUNK (2 KB) instead of whole-W (32 KB): LDS 38.9 -> 8 KB, occupancy
// cap moves from LDS (4 blk) to VGPR (~8 blk x 2 waves = 50%).
// JOURNAL: r4 global float atomics for asum = 2x slower (cross-XCD HBM RMW).
//          r6 split-K = +3.3M LDS bank conflicts in 256B-stride merge epilogue.
//          r7 aggregate via 2 arrays = 2x requests; u64 pair is load-bearing.
//          r8 bucket-hole stragglers in aggregate (clamp fixed r9).
//          r9 serial aj-gather -> part_t; r10 part_t 1024-thr.
//          r12 64-thread tile: LDS still 35KB (32KB W copy dominates) ->
//              FEWER waves/CU + 2x W restage = regression. W chunking is the fix.
__global__ __launch_bounds__(128) void k_gemm(const float* __restrict__ x,
                                              const float* __restrict__ w,
                                              const float* __restrict__ att,
                                              float* __restrict__ h,
                                              float* __restrict__ ai, float* __restrict__ aj,
                                              int N) {
  __shared__ float swc[KC * OUT_C];    // 2 KB: current W k-chunk
  __shared__ float sx[KC * SXW];       // 6 KB
  int tid = threadIdx.x;
  int rbase = blockIdx.x * 128;

  int c0 = (tid & 7) * 8;        // 8 col groups
  int rg = tid >> 3;             // 16 row groups x 8 rows
  int sxbase = rg * 12;
  float acc[8][8];
#pragma unroll
  for (int i = 0; i < 8; i++)
#pragma unroll
    for (int j = 0; j < 8; j++) acc[i][j] = 0.f;

  // x staging: thread = row; loads its row's 8 k-values (2 contiguous float4)
  int grow = rbase + tid;
  int base = (tid >> 3) * 12 + (tid & 7);   // phys(row) in a plane
  const float* xp = &x[(size_t)grow * IN_C];

  // W-chunk staging: 128 float4 per chunk; thread -> (row kb+(tid>>4), col (tid&15)*4)
  int wr = tid >> 4;
  int wc4 = (tid & 15) * 4;
  const float* wp = &w[(size_t)wr * OUT_C + wc4];

  float4 pv0 = make_float4(0.f, 0.f, 0.f, 0.f);
  float4 pv1 = make_float4(0.f, 0.f, 0.f, 0.f);
  if (grow < N) {
    pv0 = *(const float4*)&xp[0];
    pv1 = *(const float4*)&xp[4];
  }
  float4 pw = *(const float4*)&wp[0];

  for (int kb = 0; kb < IN_C; kb += KC) {
    __syncthreads();
    // commit prefetched x chunk (plane = k-within-chunk, offset = phys(row))
    sx[0 * SXW + base] = pv0.x;
    sx[1 * SXW + base] = pv0.y;
    sx[2 * SXW + base] = pv0.z;
    sx[3 * SXW + base] = pv0.w;
    sx[4 * SXW + base] = pv1.x;
    sx[5 * SXW + base] = pv1.y;
    sx[6 * SXW + base] = pv1.z;
    sx[7 * SXW + base] = pv1.w;
    // commit prefetched W chunk
    *(float4*)&swc[wr * OUT_C + wc4] = pw;
    // T14: issue next chunk's loads; latency hides under the FMA burst
    if (kb + KC < IN_C) {
      pw = *(const float4*)&wp[(size_t)(kb + KC) * OUT_C];
      if (grow < N) {
        pv0 = *(const float4*)&xp[kb + KC];
        pv1 = *(const float4*)&xp[kb + KC + 4];
      }
    }
    __syncthreads();
#pragma unroll
    for (int kl = 0; kl < KC; ++kl) {
      float xr[8], wv[8];
      *(float4*)&xr[0] = *(const float4*)&sx[kl * SXW + sxbase];
      *(float4*)&xr[4] = *(const float4*)&sx[kl * SXW + sxbase + 4];
      *(float4*)&wv[0] = *(const float4*)&swc[kl * OUT_C + c0];
      *(float4*)&wv[4] = *(const float4*)&swc[kl * OUT_C + c0 + 4];
#pragma unroll
      for (int i = 0; i < 8; ++i)
#pragma unroll
        for (int j = 0; j < 8; ++j)
          acc[i][j] += xr[i] * wv[j];
    }
  }

  float pi[8], pj[8];
#pragma unroll
  for (int i = 0; i < 8; ++i) { pi[i] = 0.f; pj[i] = 0.f; }
#pragma unroll
  for (int j = 0; j < 8; ++j) {
    float a0 = att[c0 + j], a1 = att[OUT_C + c0 + j];
#pragma unroll
    for (int i = 0; i < 8; ++i) {
      pi[i] += acc[i][j] * a0;
      pj[i] += acc[i][j] * a1;
    }
  }
#pragma unroll
  for (int o = 1; o < 8; o <<= 1) {
#pragma unroll
    for (int i = 0; i < 8; ++i) {
      pi[i] += __shfl_xor(pi[i], o);
      pj[i] += __shfl_xor(pj[i], o);
    }
  }
#pragma unroll
  for (int i = 0; i < 8; ++i) {
    int row = rbase + rg * 8 + i;
    if (row < N) {
      *(float4*)&h[(size_t)row * OUT_C + c0]     = make_float4(acc[i][0], acc[i][1], acc[i][2], acc[i][3]);
      *(float4*)&h[(size_t)row * OUT_C + c0 + 4] = make_float4(acc[i][4], acc[i][5], acc[i][6], acc[i][7]);
      if ((tid & 7) == 0) { ai[row] = pi[i]; aj[row] = pj[i]; }
    }
  }
}

// ---------------- fused tgt partition: hist + strided reservation + scatter + aj gather ----------------
__global__ __launch_bounds__(1024) void k_part_t(const int* __restrict__ src, const int* __restrict__ tgt,
                                                 const float* __restrict__ aj,
                                                 int E, int EN, int chunk,
                                                 u32* __restrict__ gcurT, u64* __restrict__ bufS,
                                                 u32* __restrict__ sel, u32 kSel) {
  __shared__ u32 lh[RBINS];
  __shared__ u32 cur[RBINS];
  int tid = threadIdx.x, b = blockIdx.x;
  if (b == 0 && tid == 0) { sel[0] = 0u; sel[1] = 0u; sel[2] = kSel; sel[3] = 0u; }
  for (int d = tid; d < RBINS; d += PTPB) lh[d] = 0u;
  __syncthreads();
  int lo = b * chunk, hi = min(lo + chunk, EN);
  for (int e = lo + tid; e < hi; e += PTPB) {
    int t = (e < E) ? tgt[e] : e - E;
    atomicAdd(&lh[((u32)t) >> 8], 1u);
  }
  __syncthreads();
  for (int d = tid; d < RBINS; d += PTPB) {
    u32 c = lh[d];
    cur[d] = c ? (u32)(d * SCAP) + atomicAdd(&gcurT[d], c) : 0u;
  }
  __syncthreads();
  for (int e = lo + tid; e < hi; e += PTPB) {
    int s, t;
    if (e < E) { s = src[e]; t = tgt[e]; } else { s = t = e - E; }
    u32 tb = ((u32)t) >> 8;
    u32 p = atomicAdd(&cur[tb], 1u);
    if (p < (tb + 1u) * SCAP) {
      float av = aj[s];
      bufS[p] = (((u64)((((u32)t & 255u) << 24) | (u32)s)) << 32) | (u64)__float_as_uint(av);
    }
  }
}

// ---------------- fine partition + CSR offsets + LDS-ONLY SOFTMAX + fused src scatter ----
__global__ __launch_bounds__(256) void k_rpass2(const u64* __restrict__ in, u32* __restrict__ out,
                                                const u32* __restrict__ gcurT, u32* __restrict__ gcurS,
                                                u32* __restrict__ offT,
                                                const float* __restrict__ ai,
                                                float* __restrict__ alpha,
                                                u64* __restrict__ pv,
                                                int N) {
  __shared__ u32 hist[256];
  __shared__ u32 sc[256];
  __shared__ u32 lhs[RBINS];
  __shared__ u32 stage[SCAP];    // 20 KB: items
  __shared__ float stageV[SCAP]; // 20 KB: aj -> a -> v -> vnorm
  int tid = threadIdx.x, d = blockIdx.x;
  u32 start = (u32)(d * SCAP);
  u32 cntb = min(gcurT[d], (u32)SCAP);
  u32 end = start + cntb;
  int sz = (int)cntb;
  hist[tid] = 0u;
  for (int dd = tid; dd < RBINS; dd += 256) lhs[dd] = 0u;
  __syncthreads();
  for (u32 p = start + tid; p < end; p += 256) {
    u32 it = (u32)(in[p] >> 32);
    atomicAdd(&hist[it >> 24], 1u);
    atomicAdd(&lhs[(it & 0xffffffu) >> 8], 1u);
  }
  __syncthreads();
  // reserve src-bucket ranges; global-atomic latency hides under scan+sort
  for (int dd = tid; dd < RBINS; dd += 256) {
    u32 c = lhs[dd];
    lhs[dd] = c ? (u32)(dd * SCAP) + atomicAdd(&gcurS[dd], c) : 0u;
  }
  u32 hv = hist[tid];
  sc[tid] = hv;
  __syncthreads();
  for (int o = 1; o < 256; o <<= 1) {
    u32 t = (tid >= o) ? sc[tid - o] : 0u;
    __syncthreads();
    sc[tid] += t;
    __syncthreads();
  }
  u32 excl = sc[tid] - hv;
  int node = (d << 8) + tid;
  if (node < N) offT[node] = start + excl;
  if (node == N - 1) offT[N] = start + sc[tid];
  hist[tid] = excl;   // running cursor
  __syncthreads();
  for (u32 p = start + tid; p < end; p += 256) {
    u64 it64 = in[p];
    u32 it = (u32)(it64 >> 32);
    u32 lp = atomicAdd(&hist[it >> 24], 1u);
    stage[lp] = it;
    stageV[lp] = __uint_as_float((u32)it64);
  }
  __syncthreads();
  // CSR items out (global writes overlap the softmax below)
  for (int i = tid; i < sz; i += 256) out[start + i] = stage[i];
  // ---- per-node softmax: pure LDS (aj pre-gathered into stageV) ----
  if (node < N) {
    int lb = (tid > 0) ? (int)sc[tid - 1] : 0;
    int le = (int)sc[tid];
    float an = ai[node];
    float mx = -1e30f;
    for (int i = lb; i < le; ++i) {
      float a = an + stageV[i];
      a = a > 0.f ? a : NEG_SLOPE * a;
      stageV[i] = a;
      mx = fmaxf(mx, a);
    }
    float sm = 0.f;
    for (int i = lb; i < le; ++i) {
      float v = expf(stageV[i] - mx);
      stageV[i] = v;
      sm += v;
    }
    float inv = 1.f / (sm + 1e-16f);
    for (int i = lb; i < le; ++i) {
      float vn = stageV[i] * inv;
      stageV[i] = vn;
      alpha[start + i] = vn;
    }
  }
  __syncthreads();
  // ---- src scatter from LDS into reserved ranges: one packed u64 per edge ----
  for (u32 p = start + tid; p < end; p += 256) {
    int i = (int)(p - start);
    u32 sp = stage[i] & 0xffffffu;
    u32 sb = sp >> 8;
    u32 pos = atomicAdd(&lhs[sb], 1u);
    if (pos < (sb + 1u) * SCAP)
      pv[pos] = (((u64)(sp & 255u)) << 32) | (u64)__float_as_uint(stageV[i]);
  }
}

// ---------------- per-bucket alpha_sum accumulation + FUSED radix pass 0 ----------------
__global__ __launch_bounds__(256) void k_asum_acc(const u64* __restrict__ pv,
                                                  const u32* __restrict__ gcurS,
                                                  float* __restrict__ asum,
                                                  u32* __restrict__ hist8, u32* __restrict__ done,
                                                  u32* __restrict__ sel, int N, int nblk) {
  __shared__ float sums[256];
  __shared__ u32 lh[256];
  __shared__ u32 s[256];
  __shared__ u32 sres;
  int tid = threadIdx.x, d = blockIdx.x;
  u32 start = (u32)(d * SCAP);
  u32 end = start + min(gcurS[d], (u32)SCAP);
  sums[tid] = 0.f;
  __syncthreads();
  for (u32 p = start + tid; p < end; p += 256) {
    u64 it = pv[p];
    atomicAdd(&sums[(u32)(it >> 32)], __uint_as_float((u32)it));
  }
  __syncthreads();
  int node = d * 256 + tid;
  u32 bin = 256u;
  if (node < N) {
    float v = sums[tid];
    asum[node] = v;
    bin = (u32)(key64(v, node) >> 56) & 255u;
  }
  lh[tid] = 0u;
  __syncthreads();
  if (bin < 256u) atomicAdd(&lh[bin], 1u);
  __syncthreads();
  if (lh[tid]) atomicAdd(&hist8[tid], lh[tid]);
  __syncthreads();
  if (tid == 0)
    sres = __hip_atomic_fetch_add(&done[0], 1u, __ATOMIC_ACQ_REL, __HIP_MEMORY_SCOPE_AGENT);
  __syncthreads();
  if (sres == (u32)(nblk - 1)) {
    u32 krem = sel[2];
    u32 hv = __hip_atomic_load(&hist8[255 - tid], __ATOMIC_RELAXED, __HIP_MEMORY_SCOPE_AGENT);
    s[tid] = hv;
    __syncthreads();
    for (int o = 1; o < 256; o <<= 1) {
      u32 t = (tid >= o) ? s[tid - o] : 0u;
      __syncthreads();
      s[tid] += t;
      __syncthreads();
    }
    u32 cum = s[tid], prev = (tid > 0) ? s[tid - 1] : 0u;
    if (cum >= krem && prev < krem) {
      ((u64*)sel)[0] = (u64)(u32)(255 - tid);
      sel[2] = krem - prev;
    }
  }
}

// ---------------- radix pass 1 (generic): hist + append + last-block pick ----------------
__global__ __launch_bounds__(256) void k_histpick(const float* __restrict__ asum,
                                                  u32* __restrict__ list_out, u32* __restrict__ cnt_out,
                                                  u32* __restrict__ hist8, u32* __restrict__ done,
                                                  u32* __restrict__ sel, int N, int nblk) {
  __shared__ u32 lh[256];
  __shared__ u32 sres;
  __shared__ u32 s[256];
  int tid = threadIdx.x;
  lh[tid] = 0u;
  __syncthreads();
  u64 prefix = ((const u64*)sel)[0];
  int i = blockIdx.x * 256 + tid;
  if (i < N) {
    u64 k = key64(asum[i], i);
    if ((k >> 56) == prefix) {
      atomicAdd(&lh[(u32)(k >> 48) & 255u], 1u);
      u32 p = atomicAdd(cnt_out, 1u);
      list_out[p] = (u32)i;
    }
  }
  __syncthreads();
  if (lh[tid]) atomicAdd(&hist8[256 + tid], lh[tid]);
  __syncthreads();
  if (tid == 0)
    sres = __hip_atomic_fetch_add(&done[1], 1u, __ATOMIC_ACQ_REL, __HIP_MEMORY_SCOPE_AGENT);
  __syncthreads();
  if (sres == (u32)(nblk - 1)) {
    u32 krem = sel[2];
    u32 hv = __hip_atomic_load(&hist8[256 + (255 - tid)], __ATOMIC_RELAXED,
                               __HIP_MEMORY_SCOPE_AGENT);
    s[tid] = hv;
    __syncthreads();
    for (int o = 1; o < 256; o <<= 1) {
      u32 t = (tid >= o) ? s[tid - o] : 0u;
      __syncthreads();
      s[tid] += t;
      __syncthreads();
    }
    u32 cum = s[tid], prev = (tid > 0) ? s[tid - 1] : 0u;
    if (cum >= krem && prev < krem) {
      ((u64*)sel)[0] = (prefix << 8) | (u64)(u32)(255 - tid);
      sel[2] = krem - prev;
    }
  }
}

// ---------------- radix pass 2 + in-block pass 3 + tie-break finish ----------------
__global__ __launch_bounds__(256) void k_histpick_final(const float* __restrict__ asum,
                                                        const u32* __restrict__ list_in, const u32* __restrict__ cnt_in,
                                                        u32* __restrict__ list_out, u32* __restrict__ cnt_out,
                                                        u32* __restrict__ hist8, u32* __restrict__ done,
                                                        u32* __restrict__ sel, int nblk) {
  __shared__ u32 lh[256];
  __shared__ u32 s[256];
  __shared__ u32 sres;
  __shared__ u64 keys[2048];
  __shared__ u32 cc;
  __shared__ u64 sprefix;
  __shared__ u32 skrem;
  int tid = threadIdx.x;
  lh[tid] = 0u;
  __syncthreads();
  u64 prefix = ((const u64*)sel)[0];   // 2 bytes
  u32 n = *cnt_in;
  u32 i = blockIdx.x * 256 + tid;
  if (i < n) {
    int idx = (int)list_in[i];
    u64 k = key64(asum[idx], idx);
    if ((k >> 48) == prefix) {
      atomicAdd(&lh[(u32)(k >> 40) & 255u], 1u);
      u32 p = atomicAdd(cnt_out, 1u);
      list_out[p] = (u32)idx;
    }
  }
  __syncthreads();
  if (lh[tid]) atomicAdd(&hist8[512 + tid], lh[tid]);
  __syncthreads();
  if (tid == 0)
    sres = __hip_atomic_fetch_add(&done[2], 1u, __ATOMIC_ACQ_REL, __HIP_MEMORY_SCOPE_AGENT);
  __syncthreads();
  if (sres != (u32)(nblk - 1)) return;
  u32 krem = sel[2];
  u32 hv = __hip_atomic_load(&hist8[512 + (255 - tid)], __ATOMIC_RELAXED, __HIP_MEMORY_SCOPE_AGENT);
  s[tid] = hv;
  __syncthreads();
  for (int o = 1; o < 256; o <<= 1) {
    u32 t = (tid >= o) ? s[tid - o] : 0u;
    __syncthreads();
    s[tid] += t;
    __syncthreads();
  }
  {
    u32 cum = s[tid], prev = (tid > 0) ? s[tid - 1] : 0u;
    if (cum >= krem && prev < krem) { sprefix = (prefix << 8) | (u64)(u32)(255 - tid); skrem = krem - prev; }
  }
  __syncthreads();
  u64 pfx3 = sprefix;
  u32 krem3 = skrem;
  u32 n3 = *cnt_out;
  lh[tid] = 0u;
  __syncthreads();
  for (u32 j = tid; j < n3; j += 256) {
    int idx = (int)list_out[j];
    u64 k = key64(asum[idx], idx);
    if ((k >> 40) == pfx3) atomicAdd(&lh[(u32)(k >> 32) & 255u], 1u);
  }
  __syncthreads();
  s[tid] = lh[255 - tid];
  __syncthreads();
  for (int o = 1; o < 256; o <<= 1) {
    u32 t = (tid >= o) ? s[tid - o] : 0u;
    __syncthreads();
    s[tid] += t;
    __syncthreads();
  }
  {
    u32 cum = s[tid], prev = (tid > 0) ? s[tid - 1] : 0u;
    if (cum >= krem3 && prev < krem3) { sprefix = (pfx3 << 8) | (u64)(u32)(255 - tid); skrem = krem3 - prev; }
  }
  if (tid == 0) cc = 0u;
  __syncthreads();
  u32 fsel = (u32)sprefix;
  u32 kremF = skrem;
  for (u32 j = tid; j < n3; j += 256) {
    int idx = (int)list_out[j];
    u64 k = key64(asum[idx], idx);
    if ((u32)(k >> 32) == fsel) {
      u32 p = atomicAdd(&cc, 1u);
      if (p < 2048) keys[p] = k;
    }
  }
  __syncthreads();
  int C = (int)min(cc, 2048u);
  for (int j = tid; j < C; j += 256) {
    u64 k = keys[j];
    u32 rank = 0;
    for (int q = 0; q < C; ++q)
      if (keys[q] > k) rank++;
    if (rank == kremF - 1) ((u64*)sel)[0] = k;
  }
}

// ---------------- node mask ----------------
__global__ __launch_bounds__(256) void k_node_mask(const float* __restrict__ asum,
                                                   const u32* __restrict__ sel,
                                                   u32* __restrict__ nm,
                                                   float* __restrict__ out_node, int N) {
  int i = blockIdx.x * 256 + threadIdx.x;
  if (i >= N) return;
  u64 T = ((const u64*)sel)[0];
  bool m = key64(asum[i], i) >= T;
  nm[i] = m ? 1u : 0u;
  out_node[i] = m ? 1.f : 0.f;
}

// ---------------- raw edge mask + premasked u64 pairs (holes skipped) ----------------
__global__ __launch_bounds__(256) void k_mask(const int* __restrict__ src, const int* __restrict__ tgt,
                                              const u32* __restrict__ nm,
                                              const u32* __restrict__ csr, const float* __restrict__ alpha,
                                              const u32* __restrict__ gcurT,
                                              float* __restrict__ out_edge, u64* __restrict__ pair,
                                              int E, int EN) {
  int q = blockIdx.x * 256 + threadIdx.x;
  if (q < EN) {
    int s, t;
    if (q < E) { s = src[q]; t = tgt[q]; } else { s = t = q - E; }
    out_edge[q] = (nm[s] && nm[t]) ? 1.f : 0.f;
  }
  if (q < SGRID) {
    u32 b = (u32)q / (u32)SCAP;
    u32 r = (u32)q - b * (u32)SCAP;
    if (r < min(gcurT[b], (u32)SCAP)) {   // holes never read (aggregate clamps)
      u32 sp = csr[q] & 0xffffffu;
      u32 ab = nm[sp] ? __float_as_uint(alpha[q]) : 0u;
      pair[q] = (((u64)sp) << 32) | ab;
    }
  }
}

// ---------------- aggregate: 8-slot pipeline, single u64 load/edge, bucket-end clamp ----------------
__global__ __launch_bounds__(256) void k_aggregate(const u32* __restrict__ off,
                                                   const u64* __restrict__ pair,
                                                   const float* __restrict__ h,
                                                   const u32* __restrict__ nm,
                                                   const u32* __restrict__ gcurT,
                                                   float* __restrict__ out, int N) {
  int node = blockIdx.x * 4 + (threadIdx.x >> 6);
  int lane = threadIdx.x & 63;
  int g = lane >> 4;
  int c = lane & 15;
  if (node >= N) return;
  float4 acc = make_float4(0.f, 0.f, 0.f, 0.f);
  if (nm[node]) {
    u32 bkt = (u32)node >> 8;
    u32 bend = bkt * (u32)SCAP + min(gcurT[bkt], (u32)SCAP);
    u32 b = off[node];
    u32 e2 = min(off[node + 1], bend);   // clamp: bucket-last node must not span holes (r8)
    for (u32 p0 = b; p0 < e2; p0 += 32) {
      u64 pr[8];
      float av[8];
      u32 sv[8];
#pragma unroll
      for (int q = 0; q < 8; ++q) {
        u32 p = p0 + q * 4 + (u32)g;
        bool ok = p < e2;
        pr[q] = pair[ok ? p : b];
        av[q] = ok ? __uint_as_float((u32)pr[q]) : 0.f;
        sv[q] = (u32)(pr[q] >> 32);
      }
      float4 hv[8];
#pragma unroll
      for (int q = 0; q < 8; ++q) {
        hv[q] = make_float4(0.f, 0.f, 0.f, 0.f);
        if (av[q] != 0.f)
          hv[q] = *(const float4*)&h[(size_t)sv[q] * OUT_C + c * 4];
      }
#pragma unroll
      for (int q = 0; q < 8; ++q) {
        acc.x += av[q] * hv[q].x;
        acc.y += av[q] * hv[q].y;
        acc.z += av[q] * hv[q].z;
        acc.w += av[q] * hv[q].w;
      }
    }
#pragma unroll
    for (int o = 16; o < 64; o <<= 1) {
      acc.x += __shfl_xor(acc.x, o);
      acc.y += __shfl_xor(acc.y, o);
      acc.z += __shfl_xor(acc.z, o);
      acc.w += __shfl_xor(acc.w, o);
    }
  }
  if (g == 0)
    *(float4*)&out[(size_t)node * OUT_C + c * 4] = acc;
}

// ---------------- launch ----------------
extern "C" void kernel_launch(void* const* d_in, const int* in_sizes, int n_in,
                              void* d_out, int out_size, void* d_ws, size_t ws_size,
                              hipStream_t stream) {
  const float* x   = (const float*)d_in[0];
  const float* w   = (const float*)d_in[1];
  const float* att = (const float*)d_in[2];
  const int*   ei  = (const int*)d_in[3];

  int N = in_sizes[0] / IN_C;
  int E = in_sizes[3] / 2;
  int EN = E + N;
  const int* src = ei;
  const int* tgt = ei + E;

  float* out      = (float*)d_out;
  float* out_edge = out + (size_t)N * OUT_C;
  float* out_node = out_edge + (size_t)EN;

  char* p = (char*)d_ws;
  auto alloc = [&](size_t bytes) -> char* {
    char* r = p;
    p += (bytes + 255) & ~(size_t)255;
    return r;
  };
  float* h     = (float*)alloc((size_t)N * OUT_C * 4);
  float* ai    = (float*)alloc((size_t)N * 4);
  float* aj    = (float*)alloc((size_t)N * 4);
  u64*   stg   = (u64*)alloc((size_t)SGRID * 8);   // part_t out: (item<<32 | f32 aj[src])
  u32*   bufA  = (u32*)alloc((size_t)SGRID * 4);   // CSR items
  float* alpha = (float*)alloc((size_t)SGRID * 4); // alpha in strided CSR order
  u64*   pv    = (u64*)alloc((size_t)SGRID * 8);   // src-pairs, then REUSED as agg pairs
  u32*   offT  = (u32*)alloc((size_t)(N + 1) * 4);
  float* asum  = (float*)alloc((size_t)N * 4);
  u32*   nm    = (u32*)alloc((size_t)N * 4);
  u32*   listA = (u32*)alloc((size_t)N * 4);
  u32*   listB = (u32*)alloc((size_t)N * 4);
  u32*   zb    = (u32*)alloc((RBINS + RBINS + 2048 + 8 + 8) * 4);
  u32*   gcurT = zb;
  u32*   gcurS = zb + RBINS;
  u32*   hist8 = zb + 2 * RBINS;
  u32*   done  = zb + 2 * RBINS + 2048;
  u32*   cnt   = zb + 2 * RBINS + 2048 + 8;
  u32*   sel   = (u32*)alloc(256);

  u64*   pair  = pv;   // alias: pv consumed by k_asum_acc before k_mask writes pair

  u32 kSel = (u32)((N + 1) / 2);
  int chunk = (EN + RB - 1) / RB;
  int gGemm = (N + 127) / 128;
  int gN = (N + 255) / 256;
  int gS = (SGRID + 255) / 256;   // covers EN too
  int gNode4 = (N + 3) / 4;

  hipMemsetAsync(zb, 0, (RBINS + RBINS + 2048 + 8 + 8) * 4, stream);

  k_gemm<<<gGemm, 128, 0, stream>>>(x, w, att, h, ai, aj, N);

  k_part_t<<<RB, PTPB, 0, stream>>>(src, tgt, aj, E, EN, chunk, gcurT, stg, sel, kSel);
  k_rpass2<<<RBINS, 256, 0, stream>>>(stg, bufA, gcurT, gcurS, offT, ai, alpha, pv, N);
  k_asum_acc<<<RBINS, 256, 0, stream>>>(pv, gcurS, asum, hist8, done, sel, N, RBINS);

  k_histpick<<<gN, 256, 0, stream>>>(asum, listA, &cnt[1], hist8, done, sel, N, gN);
  k_histpick_final<<<gN, 256, 0, stream>>>(asum, listA, &cnt[1], listB, &cnt[2],
                                           hist8, done, sel, gN);

  k_node_mask<<<gN, 256, 0, stream>>>(asum, sel, nm, out_node, N);
  k_mask<<<gS, 256, 0, stream>>>(src, tgt, nm, bufA, alpha, gcurT, out_edge, pair, E, EN);
  k_aggregate<<<gNode4, 256, 0, stream>>>(offT, pair, h, nm, gcurT, out, N);
}